// Round 6
// baseline (192.428 us; speedup 1.0000x reference)
//
#include <hip/hip_runtime.h>
#include <math.h>

#define NB 8
#define NT 2048
#define NE 1024
#define NH 64

typedef __attribute__((ext_vector_type(8))) short bh8;   // 8 x bf16 bits
typedef __attribute__((ext_vector_type(4))) float f4;    // MFMA accumulator

typedef unsigned short u16;

__device__ __forceinline__ u16 bf16rn(float f) {
    unsigned u = __float_as_uint(f);
    u += 0x7FFFu + ((u >> 16) & 1u);      // round-to-nearest-even
    return (u16)(u >> 16);
}
__device__ __forceinline__ float bf16f(u16 h) {
    return __uint_as_float(((unsigned)h) << 16);
}
// 16B-quad XOR swizzle within a 64-u16 (128B) row chunk (conflict-free b128 reads)
__device__ __forceinline__ int swzq(int quad, int row) {
    return ((quad ^ (row & 7)) << 3);
}
// async global->LDS, 16B per lane; LDS base wave-uniform (HW adds lane*16)
__device__ __forceinline__ void gll16(const u16* g, u16* l) {
    __builtin_amdgcn_global_load_lds(
        (const __attribute__((address_space(1))) unsigned int*)g,
        (__attribute__((address_space(3))) unsigned int*)l, 16, 0, 0);
}

// ---- Kernel 0: W -> (hi,lo) bf16, k-tile-major [16][192][64], 64-chunk swizzled
__global__ void wprep(const float* __restrict__ wq, const float* __restrict__ wk,
                      const float* __restrict__ wv,
                      u16* __restrict__ whi, u16* __restrict__ wlo)
{
    const int row = blockIdx.x;                       // 0..191 (q|k|v channel)
    const int k0  = threadIdx.x * 4;
    const float* src = (row < 64)  ? (wq + (size_t)row * NE)
                     : (row < 128) ? (wk + (size_t)(row - 64) * NE)
                     :               (wv + (size_t)(row - 128) * NE);
    float4 v = *(const float4*)(src + k0);
    ushort4 h, l;
    h.x = bf16rn(v.x); l.x = bf16rn(v.x - bf16f(h.x));
    h.y = bf16rn(v.y); l.y = bf16rn(v.y - bf16f(h.y));
    h.z = bf16rn(v.z); l.z = bf16rn(v.z - bf16f(h.z));
    h.w = bf16rn(v.w); l.w = bf16rn(v.w - bf16f(h.w));
    const int kt  = k0 >> 6;                 // k-tile (BK=64)
    const int kk  = k0 & 63;
    const size_t pos = (size_t)kt * (192 * 64) + row * 64 + swzq(kk >> 3, row) + (kk & 7);
    *(ushort4*)(whi + pos) = h;
    *(ushort4*)(wlo + pos) = l;
}

// ---- Kernel 1: QKV projection. 512 blocks x 256 thr; block 32 rows x 192 cols.
// W: single-buffered LDS (48 KB) staged via linear global_load_lds from the
// k-tile-contiguous pre-swizzled layout; conflict-free swizzled b128 reads.
// X (A-operand): straight from global fp32, converted in-register (no LDS).
// C = xh*wh + xh*wl + xl*wh (lo*lo dropped).
__global__ __launch_bounds__(256, 3) void qkv_mfma(
    const float* __restrict__ x, const u16* __restrict__ whi_, const u16* __restrict__ wlo_,
    u16* __restrict__ qhi, u16* __restrict__ qlo,
    u16* __restrict__ khi, u16* __restrict__ klo, u16* __restrict__ vtp)
{
    __shared__ u16 wh[192][64], wl[192][64];   // 48 KB -> 3 blocks/CU

    const int tid  = threadIdx.x;
    const int wid  = tid >> 6;
    const int lane = tid & 63;
    const int t15  = lane & 15, t4 = lane >> 4;
    const int row0 = blockIdx.x * 32;

    const f4 fzero = {0.f, 0.f, 0.f, 0.f};
    f4 acc[2][3];
#pragma unroll
    for (int m = 0; m < 2; ++m)
#pragma unroll
        for (int n = 0; n < 3; ++n) acc[m][n] = fzero;

    for (int t = 0; t < 16; ++t) {
        const int kt = t * 64;
        // issue A loads early (fly across the barriers + staging)
        float4 xr[2][2][2];                    // [ks][m][half]
#pragma unroll
        for (int ks = 0; ks < 2; ++ks)
#pragma unroll
            for (int m = 0; m < 2; ++m) {
                const float* ap = x + (size_t)(row0 + m * 16 + t15) * NE + kt + ks * 32 + t4 * 8;
                xr[ks][m][0] = *(const float4*)(ap);
                xr[ks][m][1] = *(const float4*)(ap + 4);
            }

        __syncthreads();                       // prev tile's W reads done
        // stage W tile: 12 KB hi + 12 KB lo, linear DMA (6+6 per thread)
        {
            const u16* gh = whi_ + (size_t)t * 12288;
            const u16* gl = wlo_ + (size_t)t * 12288;
#pragma unroll
            for (int it = 0; it < 6; ++it) {
                const int o = (tid + it * 256) * 8;                 // u16 offset
                const int ub = (wid * 64 + it * 256) * 8;           // wave-uniform
                gll16(gh + o, &wh[0][0] + ub);
                gll16(gl + o, &wl[0][0] + ub);
            }
        }
        __syncthreads();                       // drains vmcnt -> W visible

#pragma unroll
        for (int ks = 0; ks < 2; ++ks) {
            const int quad = 4 * ks + t4;
            // convert A fragments in-register
            bh8 ah[2], al[2];
#pragma unroll
            for (int m = 0; m < 2; ++m) {
                float f8[8];
                *(float4*)&f8[0] = xr[ks][m][0];
                *(float4*)&f8[4] = xr[ks][m][1];
#pragma unroll
                for (int j = 0; j < 8; ++j) {
                    const u16 h = bf16rn(f8[j]);
                    ah[m][j] = (short)h;
                    al[m][j] = (short)bf16rn(f8[j] - bf16f(h));
                }
            }
#pragma unroll
            for (int n = 0; n < 3; ++n) {
                const int c = wid * 48 + n * 16 + t15;
                bh8 bhv = *(const bh8*)&wh[c][swzq(quad, c)];
                bh8 blv = *(const bh8*)&wl[c][swzq(quad, c)];
#pragma unroll
                for (int m = 0; m < 2; ++m) {
                    acc[m][n] = __builtin_amdgcn_mfma_f32_16x16x32_bf16(ah[m], bhv, acc[m][n], 0, 0, 0);
                    acc[m][n] = __builtin_amdgcn_mfma_f32_16x16x32_bf16(ah[m], blv, acc[m][n], 0, 0, 0);
                    acc[m][n] = __builtin_amdgcn_mfma_f32_16x16x32_bf16(al[m], bhv, acc[m][n], 0, 0, 0);
                }
            }
        }
    }

    // epilogue: D layout col=lane&15, row=(lane>>4)*4+reg; plain outputs
#pragma unroll
    for (int m = 0; m < 2; ++m) {
#pragma unroll
        for (int n = 0; n < 3; ++n) {
            const int col = wid * 48 + n * 16 + t15;
#pragma unroll
            for (int r = 0; r < 4; ++r) {
                const int row = row0 + m * 16 + t4 * 4 + r;
                float v = acc[m][n][r];
                if (col < 64) {
                    v *= 8.0f;                         // sqrt(head_size) folded into q
                    const u16 h = bf16rn(v);
                    qhi[(size_t)row * NH + col] = h;
                    qlo[(size_t)row * NH + col] = bf16rn(v - bf16f(h));
                } else if (col < 128) {
                    const int cc = col - 64;
                    const u16 h = bf16rn(v);
                    khi[(size_t)row * NH + cc] = h;
                    klo[(size_t)row * NH + cc] = bf16rn(v - bf16f(h));
                } else {
                    const int hh  = col - 128;         // head dim
                    const int b   = row >> 11;
                    const int tok = row & (NT - 1);
                    const int cv  = tok & 63;
                    const int tp  = (tok & ~63) | ((cv & 15) * 4 + (cv >> 4)); // PV perm
                    vtp[((size_t)b * NH + hh) * NT + tp] = bf16rn(v);
                }
            }
        }
    }
}

// ---- Kernel 2: MFMA flash attention, KV-split (r3-proven structure, occ 4/CU)
__global__ __launch_bounds__(256, 4) void attn_mfma(
    const u16* __restrict__ qhi, const u16* __restrict__ qlo,
    const u16* __restrict__ khi, const u16* __restrict__ klo,
    const u16* __restrict__ vtp, const int* __restrict__ smp,
    float* __restrict__ out,
    float* __restrict__ po, float* __restrict__ pm, float* __restrict__ pl)
{
    __shared__ u16 kh[64][72], kl[64][72], vt[64][72], ps[64][72];  // 36 KB

    const int tid  = threadIdx.x;
    const int wid  = tid >> 6;
    const int lane = tid & 63;
    const int t15  = lane & 15, t4 = lane >> 4;
    const int b    = blockIdx.y;
    const int u    = 79 - (int)blockIdx.x;       // heavy chunks dispatch first
    int qt, c;
    if (u < 8)       { qt = u;                   c = 0; }
    else if (u < 24) { qt = 8  + ((u - 8) >> 1); c = (u - 8) & 1; }
    else if (u < 48) { qt = 16 + (u - 24) / 3;   c = (u - 24) % 3; }
    else             { qt = 24 + ((u - 48) >> 2); c = (u - 48) & 3; }
    const int nch   = (qt + 8) >> 3;
    const int sm    = smp[0];
    const int total = sm ? (qt + 1) : (NT / 64);
    const int jt0   = c * total / nch;
    const int jt1   = (c + 1) * total / nch;
    const int qs    = qt * 64;

    const size_t bb = (size_t)b * NT;

    // hoist Q fragments (A-frag: lane holds row=l&15, k=(l>>4)*8+j)
    bh8 qh[2], ql[2];
#pragma unroll
    for (int ks = 0; ks < 2; ++ks) {
        const size_t off = (bb + qs + wid * 16 + t15) * NH + ks * 32 + t4 * 8;
        qh[ks] = *(const bh8*)(qhi + off);
        ql[ks] = *(const bh8*)(qlo + off);
    }

    const f4 fzero = {0.f, 0.f, 0.f, 0.f};
    f4 o[4];
    float m_i[4], l_i[4];
#pragma unroll
    for (int i = 0; i < 4; ++i) { o[i] = fzero; m_i[i] = -INFINITY; l_i[i] = 0.f; }

    for (int jt = jt0; jt < jt1; ++jt) {
        const int js = jt * 64;
        __syncthreads();                       // prev iter done with kh/kl/vt/ps
        // stage K hi/lo + V^T: 512 uint4 per buffer, 2/thread each
#pragma unroll
        for (int it = 0; it < 2; ++it) {
            const int f = tid + it * 256;
            const int r = f >> 3, sg = f & 7;
            *(uint4*)&kh[r][sg * 8] = *(const uint4*)(khi + (bb + js + r) * NH + sg * 8);
            *(uint4*)&kl[r][sg * 8] = *(const uint4*)(klo + (bb + js + r) * NH + sg * 8);
            *(uint4*)&vt[r][sg * 8] = *(const uint4*)(vtp + ((size_t)b * NH + r) * NT + js + sg * 8);
        }
        __syncthreads();

        // S = (8q) k^T (split)
        f4 s[4];
#pragma unroll
        for (int n = 0; n < 4; ++n) s[n] = fzero;
#pragma unroll
        for (int n = 0; n < 4; ++n) {
#pragma unroll
            for (int ks = 0; ks < 2; ++ks) {
                const int rr = n * 16 + t15;
                bh8 bhv = *(const bh8*)&kh[rr][ks * 32 + t4 * 8];
                bh8 blv = *(const bh8*)&kl[rr][ks * 32 + t4 * 8];
                s[n] = __builtin_amdgcn_mfma_f32_16x16x32_bf16(qh[ks], bhv, s[n], 0, 0, 0);
                s[n] = __builtin_amdgcn_mfma_f32_16x16x32_bf16(qh[ks], blv, s[n], 0, 0, 0);
                s[n] = __builtin_amdgcn_mfma_f32_16x16x32_bf16(ql[ks], bhv, s[n], 0, 0, 0);
            }
        }

        // causal mask — only the diagonal tile (in the last chunk)
        if (sm && jt == qt) {
#pragma unroll
            for (int n = 0; n < 4; ++n) {
                const int col = n * 16 + t15;
#pragma unroll
                for (int r = 0; r < 4; ++r)
                    if (col > wid * 16 + t4 * 4 + r) s[n][r] = -INFINITY;
            }
        }

        // online softmax per row; stats across the 16-lane t15 groups
#pragma unroll
        for (int r = 0; r < 4; ++r) {
            float rm = fmaxf(fmaxf(s[0][r], s[1][r]), fmaxf(s[2][r], s[3][r]));
            rm = fmaxf(rm, __shfl_xor(rm, 1));
            rm = fmaxf(rm, __shfl_xor(rm, 2));
            rm = fmaxf(rm, __shfl_xor(rm, 4));
            rm = fmaxf(rm, __shfl_xor(rm, 8));
            const float mn = fmaxf(m_i[r], rm);
            const float cf = __expf(m_i[r] - mn);
            const float p0 = __expf(s[0][r] - mn);
            const float p1 = __expf(s[1][r] - mn);
            const float p2 = __expf(s[2][r] - mn);
            const float p3 = __expf(s[3][r] - mn);
            float rs = p0 + p1 + p2 + p3;
            rs += __shfl_xor(rs, 1);
            rs += __shfl_xor(rs, 2);
            rs += __shfl_xor(rs, 4);
            rs += __shfl_xor(rs, 8);
            l_i[r] = l_i[r] * cf + rs;
            m_i[r] = mn;
#pragma unroll
            for (int hs = 0; hs < 4; ++hs) o[hs][r] *= cf;
            ushort4 pw;
            pw.x = bf16rn(p0); pw.y = bf16rn(p1); pw.z = bf16rn(p2); pw.w = bf16rn(p3);
            // P'[row][p], p = t15*4 + n  (matches vtp permutation)
            *(ushort4*)&ps[wid * 16 + t4 * 4 + r][t15 * 4] = pw;
        }

        // O += P' V'  (permuted k-index matches vtp permutation)
#pragma unroll
        for (int ks = 0; ks < 2; ++ks) {
            bh8 pa = *(const bh8*)&ps[wid * 16 + t15][ks * 32 + t4 * 8];
#pragma unroll
            for (int hs = 0; hs < 4; ++hs) {
                bh8 bv = *(const bh8*)&vt[hs * 16 + t15][ks * 32 + t4 * 8];
                o[hs] = __builtin_amdgcn_mfma_f32_16x16x32_bf16(pa, bv, o[hs], 0, 0, 0);
            }
        }
    }

    if (nch == 1) {
        // final: normalize + write fp32
#pragma unroll
        for (int r = 0; r < 4; ++r) {
            const float inv = 1.0f / l_i[r];
            const size_t rowoff = (bb + qs + wid * 16 + t4 * 4 + r) * NH;
#pragma unroll
            for (int hs = 0; hs < 4; ++hs)
                out[rowoff + hs * 16 + t15] = o[hs][r] * inv;
        }
    } else {
        // partial: unnormalized o + per-row (m, l)
        const int slot = (b * 24 + (qt - 8)) * 4 + c;
        float* pop = po + (size_t)slot * 64 * 64;
#pragma unroll
        for (int r = 0; r < 4; ++r) {
            const int rl = wid * 16 + t4 * 4 + r;
#pragma unroll
            for (int hs = 0; hs < 4; ++hs)
                pop[(size_t)rl * 64 + hs * 16 + t15] = o[hs][r];
            if (t15 == 0) {
                pm[(size_t)slot * 64 + rl] = m_i[r];
                pl[(size_t)slot * 64 + rl] = l_i[r];
            }
        }
    }
}

// ---- Kernel 3: combine KV-split partials (exact online-softmax merge)
__global__ void attn_combine(const float* __restrict__ po, const float* __restrict__ pm,
                             const float* __restrict__ pl, float* __restrict__ out)
{
    const int qt  = 8 + (int)blockIdx.x;
    const int b   = blockIdx.y;
    const int nch = (qt + 8) >> 3;
    const int tid = threadIdx.x;
    const int r   = tid >> 2;              // 0..63
    const int h0  = (tid & 3) * 16;        // 16 h per thread
    const int base = (b * 24 + (qt - 8)) * 4;

    float m[4], w[4];
    float M = -INFINITY;
#pragma unroll
    for (int cc = 0; cc < 4; ++cc) {
        m[cc] = (cc < nch) ? pm[(size_t)(base + cc) * 64 + r] : -INFINITY;
        M = fmaxf(M, m[cc]);
    }
    float denom = 0.f;
#pragma unroll
    for (int cc = 0; cc < 4; ++cc) {
        w[cc] = (cc < nch) ? __expf(m[cc] - M) : 0.f;
        denom += ((cc < nch) ? pl[(size_t)(base + cc) * 64 + r] : 0.f) * w[cc];
    }
    const float inv = 1.0f / denom;

    const size_t orow = ((size_t)b * NT + (size_t)qt * 64 + r) * NH;
#pragma unroll
    for (int v = 0; v < 4; ++v) {
        float4 acc = make_float4(0.f, 0.f, 0.f, 0.f);
#pragma unroll
        for (int cc = 0; cc < 4; ++cc) {
            if (cc < nch) {
                float4 pv = *(const float4*)(po + ((size_t)(base + cc) * 64 + r) * 64 + h0 + v * 4);
                acc.x += pv.x * w[cc]; acc.y += pv.y * w[cc];
                acc.z += pv.z * w[cc]; acc.w += pv.w * w[cc];
            }
        }
        acc.x *= inv; acc.y *= inv; acc.z *= inv; acc.w *= inv;
        *(float4*)(out + orow + h0 + v * 4) = acc;
    }
}

extern "C" void kernel_launch(void* const* d_in, const int* in_sizes, int n_in,
                              void* d_out, int out_size, void* d_ws, size_t ws_size,
                              hipStream_t stream)
{
    const float* x  = (const float*)d_in[0];
    const float* wq = (const float*)d_in[1];
    const float* wk = (const float*)d_in[2];
    const float* wv = (const float*)d_in[3];
    const int*   sm = (const int*)d_in[4];
    float* out = (float*)d_out;

    u16* whi = (u16*)d_ws;                       // [16][192][64] k-tile-major swz
    u16* wlo = whi + (size_t)192 * NE;
    u16* qhi = wlo + (size_t)192 * NE;           // [B*T][64] each (plain)
    u16* qlo = qhi + (size_t)NB * NT * NH;
    u16* khi = qlo + (size_t)NB * NT * NH;
    u16* klo = khi + (size_t)NB * NT * NH;
    u16* vtp = klo + (size_t)NB * NT * NH;       // [B][64][2048] permuted (plain)
    float* po = (float*)(vtp + (size_t)NB * NT * NH);  // [8*24*4][64][64]
    float* pm = po + (size_t)NB * 24 * 4 * 64 * 64;    // [8*24*4][64]
    float* pl = pm + (size_t)NB * 24 * 4 * 64;

    wprep<<<dim3(192), 256, 0, stream>>>(wq, wk, wv, whi, wlo);
    qkv_mfma<<<dim3((NB * NT) / 32), 256, 0, stream>>>(x, whi, wlo, qhi, qlo, khi, klo, vtp);
    attn_mfma<<<dim3(80, NB), 256, 0, stream>>>(qhi, qlo, khi, klo, vtp, sm, out, po, pm, pl);
    attn_combine<<<dim3(24, NB), 256, 0, stream>>>(po, pm, pl, out);
}

// Round 9
// 160.046 us; speedup vs baseline: 1.2023x; 1.2023x over previous
//
#include <hip/hip_runtime.h>
#include <math.h>

#define NB 8
#define NT 2048
#define NE 1024
#define NH 64

typedef __attribute__((ext_vector_type(8))) short bh8;   // 8 x bf16 bits
typedef __attribute__((ext_vector_type(4))) float f4;    // MFMA accumulator

typedef unsigned short u16;

__device__ __forceinline__ u16 bf16rn(float f) {
    unsigned u = __float_as_uint(f);
    u += 0x7FFFu + ((u >> 16) & 1u);      // round-to-nearest-even
    return (u16)(u >> 16);
}
__device__ __forceinline__ float bf16f(u16 h) {
    return __uint_as_float(((unsigned)h) << 16);
}

// ---------------- Kernel 0: W -> (hi, lo) bf16, concatenated [192][1024] ----
__global__ void wprep(const float* __restrict__ wq, const float* __restrict__ wk,
                      const float* __restrict__ wv,
                      u16* __restrict__ whi, u16* __restrict__ wlo)
{
    const int row = blockIdx.x;                       // 0..191
    const int k0  = threadIdx.x * 4;
    const float* src = (row < 64)  ? (wq + (size_t)row * NE)
                     : (row < 128) ? (wk + (size_t)(row - 64) * NE)
                     :               (wv + (size_t)(row - 128) * NE);
    float4 v = *(const float4*)(src + k0);
    ushort4 h, l;
    h.x = bf16rn(v.x); l.x = bf16rn(v.x - bf16f(h.x));
    h.y = bf16rn(v.y); l.y = bf16rn(v.y - bf16f(h.y));
    h.z = bf16rn(v.z); l.z = bf16rn(v.z - bf16f(h.z));
    h.w = bf16rn(v.w); l.w = bf16rn(v.w - bf16f(h.w));
    *(ushort4*)(whi + (size_t)row * NE + k0) = h;
    *(ushort4*)(wlo + (size_t)row * NE + k0) = l;
}

// ---------------- Kernel 1: QKV projection via split-bf16 MFMA ---------------
// 512 blocks x 256 thr. Block: 32 rows x 192 cols, BK=64 (proven r3 structure).
// Wave w: cols [48w,48w+48). C = xh*wh + xh*wl + xl*wh (lo*lo dropped).
__global__ __launch_bounds__(256, 2) void qkv_mfma(
    const float* __restrict__ x, const u16* __restrict__ whi_, const u16* __restrict__ wlo_,
    u16* __restrict__ qhi, u16* __restrict__ qlo,
    u16* __restrict__ khi, u16* __restrict__ klo, u16* __restrict__ vtp)
{
    __shared__ u16 xh[32][72], xl[32][72];     // row stride 144B
    __shared__ u16 wh[192][72], wl[192][72];

    const int tid  = threadIdx.x;
    const int wid  = tid >> 6;
    const int lane = tid & 63;
    const int t15  = lane & 15, t4 = lane >> 4;
    const int row0 = blockIdx.x * 32;

    const f4 fzero = {0.f, 0.f, 0.f, 0.f};
    f4 acc[2][3];
#pragma unroll
    for (int m = 0; m < 2; ++m)
#pragma unroll
        for (int n = 0; n < 3; ++n) acc[m][n] = fzero;

    for (int kt = 0; kt < NE; kt += 64) {
        __syncthreads();
        // stage X tile (32x64 fp32 -> hi/lo bf16): 512 float4, 2/thread
#pragma unroll
        for (int it = 0; it < 2; ++it) {
            const int f = tid + it * 256;
            const int r = f >> 4, sg = f & 15;
            float4 v = *(const float4*)(x + (size_t)(row0 + r) * NE + kt + sg * 4);
            ushort4 h, l;
            h.x = bf16rn(v.x); l.x = bf16rn(v.x - bf16f(h.x));
            h.y = bf16rn(v.y); l.y = bf16rn(v.y - bf16f(h.y));
            h.z = bf16rn(v.z); l.z = bf16rn(v.z - bf16f(h.z));
            h.w = bf16rn(v.w); l.w = bf16rn(v.w - bf16f(h.w));
            *(ushort4*)&xh[r][sg * 4] = h;
            *(ushort4*)&xl[r][sg * 4] = l;
        }
        // stage W tile (192x64 bf16 hi+lo): 1536 uint4 per buffer, 6/thread
#pragma unroll
        for (int it = 0; it < 6; ++it) {
            const int f = tid + it * 256;
            const int r = f >> 3, sg = f & 7;
            *(uint4*)&wh[r][sg * 8] = *(const uint4*)(whi_ + (size_t)r * NE + kt + sg * 8);
            *(uint4*)&wl[r][sg * 8] = *(const uint4*)(wlo_ + (size_t)r * NE + kt + sg * 8);
        }
        __syncthreads();

#pragma unroll
        for (int ks = 0; ks < 2; ++ks) {
            bh8 ah[2], al[2];
#pragma unroll
            for (int m = 0; m < 2; ++m) {
                ah[m] = *(const bh8*)&xh[m * 16 + t15][ks * 32 + t4 * 8];
                al[m] = *(const bh8*)&xl[m * 16 + t15][ks * 32 + t4 * 8];
            }
#pragma unroll
            for (int n = 0; n < 3; ++n) {
                const int c = wid * 48 + n * 16 + t15;
                bh8 bhv = *(const bh8*)&wh[c][ks * 32 + t4 * 8];
                bh8 blv = *(const bh8*)&wl[c][ks * 32 + t4 * 8];
#pragma unroll
                for (int m = 0; m < 2; ++m) {
                    acc[m][n] = __builtin_amdgcn_mfma_f32_16x16x32_bf16(ah[m], bhv, acc[m][n], 0, 0, 0);
                    acc[m][n] = __builtin_amdgcn_mfma_f32_16x16x32_bf16(ah[m], blv, acc[m][n], 0, 0, 0);
                    acc[m][n] = __builtin_amdgcn_mfma_f32_16x16x32_bf16(al[m], bhv, acc[m][n], 0, 0, 0);
                }
            }
        }
    }

    // epilogue: D layout col=lane&15, row=(lane>>4)*4+reg
#pragma unroll
    for (int m = 0; m < 2; ++m) {
#pragma unroll
        for (int n = 0; n < 3; ++n) {
            const int col = wid * 48 + n * 16 + t15;
#pragma unroll
            for (int r = 0; r < 4; ++r) {
                const int row = row0 + m * 16 + t4 * 4 + r;
                float v = acc[m][n][r];
                if (col < 64) {
                    v *= 8.0f;                         // sqrt(head_size) folded into q
                    const u16 h = bf16rn(v);
                    qhi[(size_t)row * NH + col] = h;
                    qlo[(size_t)row * NH + col] = bf16rn(v - bf16f(h));
                } else if (col < 128) {
                    const u16 h = bf16rn(v);
                    khi[(size_t)row * NH + (col - 64)] = h;
                    klo[(size_t)row * NH + (col - 64)] = bf16rn(v - bf16f(h));
                } else {
                    const int b   = row >> 11;
                    const int tok = row & (NT - 1);
                    const int c   = tok & 63;
                    const int tp  = (tok & ~63) | ((c & 15) * 4 + (c >> 4)); // p(c)
                    vtp[((size_t)b * NH + (col - 128)) * NT + tp] = bf16rn(v);
                }
            }
        }
    }
}

// ---------------- Kernel 2: MFMA flash attention, KV-split -------------------
// grid (80, 8) x 256 thr. q-tile 64 (wave w: rows 16w..16w+15), kv-tile 64.
// Per (b,qt): nch=(qt+8)/8 chunks, one block each. r3 structure, occ 4/CU.
// Partials: NORMALIZED o in bf16 (+ m, l fp32) -> halves ws poison + traffic.
__global__ __launch_bounds__(256, 4) void attn_mfma(
    const u16* __restrict__ qhi, const u16* __restrict__ qlo,
    const u16* __restrict__ khi, const u16* __restrict__ klo,
    const u16* __restrict__ vtp, const int* __restrict__ smp,
    float* __restrict__ out,
    u16* __restrict__ po, float* __restrict__ pm, float* __restrict__ pl)
{
    __shared__ u16 kh[64][72], kl[64][72], vt[64][72], ps[64][72];  // 36 KB

    const int tid  = threadIdx.x;
    const int wid  = tid >> 6;
    const int lane = tid & 63;
    const int t15  = lane & 15, t4 = lane >> 4;
    const int b    = blockIdx.y;
    const int u    = 79 - (int)blockIdx.x;       // heavy chunks dispatch first
    int qt, c;
    if (u < 8)       { qt = u;                   c = 0; }
    else if (u < 24) { qt = 8  + ((u - 8) >> 1); c = (u - 8) & 1; }
    else if (u < 48) { qt = 16 + (u - 24) / 3;   c = (u - 24) % 3; }
    else             { qt = 24 + ((u - 48) >> 2); c = (u - 48) & 3; }
    const int nch   = (qt + 8) >> 3;
    const int sm    = smp[0];
    const int total = sm ? (qt + 1) : (NT / 64);
    const int jt0   = c * total / nch;
    const int jt1   = (c + 1) * total / nch;
    const int qs    = qt * 64;

    const size_t bb = (size_t)b * NT;

    // hoist Q fragments (A-frag: lane holds row=l&15, k=(l>>4)*8+j)
    bh8 qh[2], ql[2];
#pragma unroll
    for (int ks = 0; ks < 2; ++ks) {
        const size_t off = (bb + qs + wid * 16 + t15) * NH + ks * 32 + t4 * 8;
        qh[ks] = *(const bh8*)(qhi + off);
        ql[ks] = *(const bh8*)(qlo + off);
    }

    const f4 fzero = {0.f, 0.f, 0.f, 0.f};
    f4 o[4];
    float m_i[4], l_i[4];
#pragma unroll
    for (int i = 0; i < 4; ++i) { o[i] = fzero; m_i[i] = -INFINITY; l_i[i] = 0.f; }

    for (int jt = jt0; jt < jt1; ++jt) {
        const int js = jt * 64;
        __syncthreads();                       // prev iter done with kh/kl/vt/ps
        // stage K hi/lo + V^T: 512 uint4 per buffer, 2/thread each
#pragma unroll
        for (int it = 0; it < 2; ++it) {
            const int f = tid + it * 256;
            const int r = f >> 3, sg = f & 7;
            *(uint4*)&kh[r][sg * 8] = *(const uint4*)(khi + (bb + js + r) * NH + sg * 8);
            *(uint4*)&kl[r][sg * 8] = *(const uint4*)(klo + (bb + js + r) * NH + sg * 8);
            *(uint4*)&vt[r][sg * 8] = *(const uint4*)(vtp + ((size_t)b * NH + r) * NT + js + sg * 8);
        }
        __syncthreads();

        // S = (8q) k^T (split)
        f4 s[4];
#pragma unroll
        for (int n = 0; n < 4; ++n) s[n] = fzero;
#pragma unroll
        for (int n = 0; n < 4; ++n) {
#pragma unroll
            for (int ks = 0; ks < 2; ++ks) {
                const int rr = n * 16 + t15;
                bh8 bhv = *(const bh8*)&kh[rr][ks * 32 + t4 * 8];
                bh8 blv = *(const bh8*)&kl[rr][ks * 32 + t4 * 8];
                s[n] = __builtin_amdgcn_mfma_f32_16x16x32_bf16(qh[ks], bhv, s[n], 0, 0, 0);
                s[n] = __builtin_amdgcn_mfma_f32_16x16x32_bf16(qh[ks], blv, s[n], 0, 0, 0);
                s[n] = __builtin_amdgcn_mfma_f32_16x16x32_bf16(ql[ks], bhv, s[n], 0, 0, 0);
            }
        }

        // causal mask — only the diagonal tile (in the last chunk)
        if (sm && jt == qt) {
#pragma unroll
            for (int n = 0; n < 4; ++n) {
                const int col = n * 16 + t15;
#pragma unroll
                for (int r = 0; r < 4; ++r)
                    if (col > wid * 16 + t4 * 4 + r) s[n][r] = -INFINITY;
            }
        }

        // online softmax per row; stats across the 16-lane t15 groups
#pragma unroll
        for (int r = 0; r < 4; ++r) {
            float rm = fmaxf(fmaxf(s[0][r], s[1][r]), fmaxf(s[2][r], s[3][r]));
            rm = fmaxf(rm, __shfl_xor(rm, 1));
            rm = fmaxf(rm, __shfl_xor(rm, 2));
            rm = fmaxf(rm, __shfl_xor(rm, 4));
            rm = fmaxf(rm, __shfl_xor(rm, 8));
            const float mn = fmaxf(m_i[r], rm);
            const float cf = __expf(m_i[r] - mn);
            const float p0 = __expf(s[0][r] - mn);
            const float p1 = __expf(s[1][r] - mn);
            const float p2 = __expf(s[2][r] - mn);
            const float p3 = __expf(s[3][r] - mn);
            float rs = p0 + p1 + p2 + p3;
            rs += __shfl_xor(rs, 1);
            rs += __shfl_xor(rs, 2);
            rs += __shfl_xor(rs, 4);
            rs += __shfl_xor(rs, 8);
            l_i[r] = l_i[r] * cf + rs;
            m_i[r] = mn;
#pragma unroll
            for (int hs = 0; hs < 4; ++hs) o[hs][r] *= cf;
            ushort4 pw;
            pw.x = bf16rn(p0); pw.y = bf16rn(p1); pw.z = bf16rn(p2); pw.w = bf16rn(p3);
            // P'[row][p], p = t15*4 + n  (matches vtp permutation)
            *(ushort4*)&ps[wid * 16 + t4 * 4 + r][t15 * 4] = pw;
        }

        // O += P' V'  (permuted k-index matches vtp permutation)
#pragma unroll
        for (int ks = 0; ks < 2; ++ks) {
            bh8 pa = *(const bh8*)&ps[wid * 16 + t15][ks * 32 + t4 * 8];
#pragma unroll
            for (int hs = 0; hs < 4; ++hs) {
                bh8 bv = *(const bh8*)&vt[hs * 16 + t15][ks * 32 + t4 * 8];
                o[hs] = __builtin_amdgcn_mfma_f32_16x16x32_bf16(pa, bv, o[hs], 0, 0, 0);
            }
        }
    }

    if (nch == 1) {
        // final: normalize + write fp32
#pragma unroll
        for (int r = 0; r < 4; ++r) {
            const float inv = 1.0f / l_i[r];
            const size_t rowoff = (bb + qs + wid * 16 + t4 * 4 + r) * NH;
#pragma unroll
            for (int hs = 0; hs < 4; ++hs)
                out[rowoff + hs * 16 + t15] = o[hs][r] * inv;
        }
    } else {
        // partial: normalized o (bf16) + per-row (m, l) fp32
        const int slot = (b * 24 + (qt - 8)) * 4 + c;
        u16* pop = po + (size_t)slot * 64 * 64;
#pragma unroll
        for (int r = 0; r < 4; ++r) {
            const int rl = wid * 16 + t4 * 4 + r;
            const float inv = 1.0f / l_i[r];
#pragma unroll
            for (int hs = 0; hs < 4; ++hs)
                pop[(size_t)rl * 64 + hs * 16 + t15] = bf16rn(o[hs][r] * inv);
            if (t15 == 0) {
                pm[(size_t)slot * 64 + rl] = m_i[r];
                pl[(size_t)slot * 64 + rl] = l_i[r];
            }
        }
    }
}

// ---- Kernel 3: combine KV-split partials (merge of per-chunk normalized o)
__global__ void attn_combine(const u16* __restrict__ po, const float* __restrict__ pm,
                             const float* __restrict__ pl, float* __restrict__ out)
{
    const int qt  = 8 + (int)blockIdx.x;
    const int b   = blockIdx.y;
    const int nch = (qt + 8) >> 3;
    const int tid = threadIdx.x;
    const int r   = tid >> 2;              // 0..63
    const int h0  = (tid & 3) * 16;        // 16 h per thread
    const int base = (b * 24 + (qt - 8)) * 4;

    float m[4], w[4];
    float M = -INFINITY;
#pragma unroll
    for (int cc = 0; cc < 4; ++cc) {
        m[cc] = (cc < nch) ? pm[(size_t)(base + cc) * 64 + r] : -INFINITY;
        M = fmaxf(M, m[cc]);
    }
    float denom = 0.f;
#pragma unroll
    for (int cc = 0; cc < 4; ++cc) {
        // weight = l_cc * exp(m_cc - M); o_cc stored normalized (o/l)
        w[cc] = (cc < nch) ? pl[(size_t)(base + cc) * 64 + r] * __expf(m[cc] - M) : 0.f;
        denom += w[cc];
    }
    const float inv = 1.0f / denom;

    const size_t orow = ((size_t)b * NT + (size_t)qt * 64 + r) * NH;
#pragma unroll
    for (int v = 0; v < 2; ++v) {
        float acc8[8] = {0.f,0.f,0.f,0.f,0.f,0.f,0.f,0.f};
#pragma unroll
        for (int cc = 0; cc < 4; ++cc) {
            if (cc < nch) {
                ushort4 pv = *(const ushort4*)(po + ((size_t)(base + cc) * 64 + r) * 64 + h0 + v * 8);
                ushort4 pv2 = *(const ushort4*)(po + ((size_t)(base + cc) * 64 + r) * 64 + h0 + v * 8 + 4);
                acc8[0] += bf16f(pv.x)  * w[cc]; acc8[1] += bf16f(pv.y)  * w[cc];
                acc8[2] += bf16f(pv.z)  * w[cc]; acc8[3] += bf16f(pv.w)  * w[cc];
                acc8[4] += bf16f(pv2.x) * w[cc]; acc8[5] += bf16f(pv2.y) * w[cc];
                acc8[6] += bf16f(pv2.z) * w[cc]; acc8[7] += bf16f(pv2.w) * w[cc];
            }
        }
        float4 o0 = make_float4(acc8[0]*inv, acc8[1]*inv, acc8[2]*inv, acc8[3]*inv);
        float4 o1 = make_float4(acc8[4]*inv, acc8[5]*inv, acc8[6]*inv, acc8[7]*inv);
        *(float4*)(out + orow + h0 + v * 8)     = o0;
        *(float4*)(out + orow + h0 + v * 8 + 4) = o1;
    }
}

extern "C" void kernel_launch(void* const* d_in, const int* in_sizes, int n_in,
                              void* d_out, int out_size, void* d_ws, size_t ws_size,
                              hipStream_t stream)
{
    const float* x  = (const float*)d_in[0];
    const float* wq = (const float*)d_in[1];
    const float* wk = (const float*)d_in[2];
    const float* wv = (const float*)d_in[3];
    const int*   sm = (const int*)d_in[4];
    float* out = (float*)d_out;

    u16* whi = (u16*)d_ws;                       // [192][1024]
    u16* wlo = whi + (size_t)192 * NE;
    u16* qhi = wlo + (size_t)192 * NE;           // [B*T][64] each
    u16* qlo = qhi + (size_t)NB * NT * NH;
    u16* khi = qlo + (size_t)NB * NT * NH;
    u16* klo = khi + (size_t)NB * NT * NH;
    u16* vtp = klo + (size_t)NB * NT * NH;       // [B][64][2048] permuted
    u16* po  = vtp + (size_t)NB * NT * NH;       // [8*24*4][64][64] bf16 norm'd
    float* pm = (float*)(po + (size_t)NB * 24 * 4 * 64 * 64);  // [8*24*4][64]
    float* pl = pm + (size_t)NB * 24 * 4 * 64;

    wprep<<<dim3(192), 256, 0, stream>>>(wq, wk, wv, whi, wlo);
    qkv_mfma<<<dim3((NB * NT) / 32), 256, 0, stream>>>(x, whi, wlo, qhi, qlo, khi, klo, vtp);
    attn_mfma<<<dim3(80, NB), 256, 0, stream>>>(qhi, qlo, khi, klo, vtp, sm, out, po, pm, pl);
    attn_combine<<<dim3(24, NB), 256, 0, stream>>>(po, pm, pl, out);
}